// Round 13
// baseline (3448.273 us; speedup 1.0000x reference)
//
#include <hip/hip_runtime.h>
#include <math.h>

// Neural Hawkes scan. B=256,T=512,H=512,E=32.
// R13 = R9 (best verified, 2264us) minus the producer-drain round-trip:
//  - h published as R6-proven tagged 8B units {fp16x2, step} via sc0 sc1
//    dwordx2 (single-copy atomic). NO vmcnt drain before flag publish --
//    the tag IS the data-integrity proof; consumer verifies at fetch and
//    retries (bounded, expected ~0: flag RT + detect + fetch >> store skew).
//  - per-WAVE flags published right after the wave's own EW+stores; the
//    red-protection __syncthreads moves AFTER the flag store (overlaps
//    fabric). Consumer wave polls its 16 producer-wave flags = one 64B line.
//  - watchdog budgets sized so systematic failure -> wrong answer in <2s,
//    never a bench timeout (R12 lesson: an over-budget watchdog IS a hang).
// Carriers all sc0 sc1 (R4/R7/R12: consumer-cacheable polling of remote
// stores is unusable on this chip -- direction permanently closed).

#define Bb   256
#define Tt   512
#define Hh   512
#define Ee   32
#define G5H  2560
#define NTHR 256
#define RT   16
#define CT   32

typedef __attribute__((ext_vector_type(8))) short f16x8;
typedef __attribute__((ext_vector_type(4))) float f32x4;
typedef __attribute__((ext_vector_type(4))) unsigned u32x4;
typedef __attribute__((ext_vector_type(2))) unsigned u32x2;

__device__ __forceinline__ float softplusf(float x) {
    return fmaxf(x, 0.f) + __logf(1.f + __expf(-fabsf(x)));
}
__device__ __forceinline__ float fast_tanh(float x) {
    const float t = fminf(fmaxf(x, -15.f), 15.f);
    const float e = __expf(2.f * t);
    return (e - 1.f) / (e + 1.f);
}
__device__ __forceinline__ unsigned short f2h(float f) {
    _Float16 h = (_Float16)f;
    return *reinterpret_cast<unsigned short*>(&h);
}

// 8x 16B L3-coherent loads of tagged units (kk-th 32B chunk at byte kk*128).
__device__ __forceinline__ void load_tagged8(const unsigned* p, u32x4 (&d)[8]) {
    asm volatile(
        "global_load_dwordx4 %0, %8, off sc0 sc1\n\t"
        "global_load_dwordx4 %1, %8, off offset:16 sc0 sc1\n\t"
        "global_load_dwordx4 %2, %8, off offset:128 sc0 sc1\n\t"
        "global_load_dwordx4 %3, %8, off offset:144 sc0 sc1\n\t"
        "global_load_dwordx4 %4, %8, off offset:256 sc0 sc1\n\t"
        "global_load_dwordx4 %5, %8, off offset:272 sc0 sc1\n\t"
        "global_load_dwordx4 %6, %8, off offset:384 sc0 sc1\n\t"
        "global_load_dwordx4 %7, %8, off offset:400 sc0 sc1\n\t"
        "s_waitcnt vmcnt(0)"
        : "=&v"(d[0]), "=&v"(d[1]), "=&v"(d[2]), "=&v"(d[3]),
          "=&v"(d[4]), "=&v"(d[5]), "=&v"(d[6]), "=&v"(d[7])
        : "v"(p) : "memory");
}
__device__ __forceinline__ void st_tag(unsigned* p, unsigned data, unsigned tag) {
    u32x2 v; v.x = data; v.y = tag;
    asm volatile("global_store_dwordx2 %0, %1, off sc0 sc1"
                 :: "v"(p), "v"(v) : "memory");
}
__device__ __forceinline__ void st_u32_sc(void* p, unsigned v) {
    asm volatile("global_store_dword %0, %1, off sc0 sc1"
                 :: "v"(p), "v"(v) : "memory");
}
__device__ __forceinline__ unsigned ld_u32_sc(const unsigned* p) {
    unsigned v;
    asm volatile("global_load_dword %0, %1, off sc0 sc1\n\ts_waitcnt vmcnt(0)"
                 : "=v"(v) : "v"(p) : "memory");
    return v;
}

__global__ __launch_bounds__(NTHR, 1)
void nhp_scan(const int* __restrict__ events, const float* __restrict__ times,
              const float* __restrict__ emb, const float* __restrict__ Wg,
              const float* __restrict__ bg, float* __restrict__ out_hid,
              unsigned* __restrict__ flags, unsigned* __restrict__ hb) {
    __shared__ float red[4][10][16][18];        // [ksplit][tile][row][col+pad] 46KB
    __shared__ float gx[Ee][5][34];             // col XOR-swizzled by (e&7)<<2
    __shared__ float dt_lds[RT][516];           // all dt, bank-padded
    __shared__ unsigned char ev_lds[RT][520];   // all events

    const int tid  = threadIdx.x, bid = blockIdx.x;
    const int rt   = bid & 15;        // row group
    const int ct   = bid >> 4;        // col tile
    const int r0   = rt * RT;
    const int lane = tid & 63;
    const int ks   = tid >> 6;        // wave id == 4-way K split
    const int frow = lane & 15, kgrp = lane >> 4;
    const int erow = tid >> 4;        // elementwise row 0..15 (wave ks: rows 4ks..4ks+3)
    const int ecp  = (tid & 15) * 2;  // elementwise col pair

    // ---- one-time: precache events + dt for this block's 16 rows (all T)
    for (int u = tid; u < RT * Tt; u += NTHR) {
        const int row = u >> 9, pp = u & 511;
        const float t1 = times[(r0 + row) * Tt + pp];
        const float t0 = pp ? times[(r0 + row) * Tt + pp - 1] : 0.f;
        dt_lds[row][pp] = t1 - t0;
        ev_lds[row][pp] = (unsigned char)events[(r0 + row) * Tt + pp];
    }

    // ---- one-time: gx[e][g][hc] = emb[e] @ Wx[:,col] + b (XOR-swizzled store)
    for (int u = tid; u < Ee * 5 * CT; u += NTHR) {
        const int e = u / 160, r = u - e * 160;
        const int g = r >> 5, hc = r & 31;
        const int gcol = g * Hh + ct * CT + hc;
        float acc = bg[gcol];
        const float* er = emb + (size_t)e * Hh;
        for (int k = 0; k < Hh; k += 4) {
            acc += er[k]     * Wg[(size_t)k       * G5H + gcol];
            acc += er[k + 1] * Wg[(size_t)(k + 1) * G5H + gcol];
            acc += er[k + 2] * Wg[(size_t)(k + 2) * G5H + gcol];
            acc += er[k + 3] * Wg[(size_t)(k + 3) * G5H + gcol];
        }
        gx[e][g][hc ^ ((e & 7) << 2)] = acc;
    }

    // ---- one-time: Wh fp16 B-fragments, register-resident for all T steps
    f16x8 Bf[10][4];
    #pragma unroll
    for (int n = 0; n < 10; ++n) {
        const int col = (n >> 1) * Hh + ct * CT + (n & 1) * 16 + frow;
        #pragma unroll
        for (int kk = 0; kk < 4; ++kk) {
            const int k0 = ks * 128 + kk * 32 + kgrp * 8;
            union { f16x8 v; unsigned u[4]; } tmp;
            #pragma unroll
            for (int r = 0; r < 4; ++r) {
                const float w0 = Wg[(size_t)(Hh + k0 + 2 * r)     * G5H + col];
                const float w1 = Wg[(size_t)(Hh + k0 + 2 * r + 1) * G5H + col];
                tmp.u[r] = (unsigned)f2h(w0) | ((unsigned)f2h(w1) << 16);
            }
            Bf[n][kk] = tmp.v;
        }
    }

    float cA = 0.f, cB = 0.f;
    __syncthreads();

    for (int p = 0; p < Tt; ++p) {
        if (p > 0) {
            // ---- poll 16 producer-wave flags (blocks 4ks..4ks+3 x waves 0..3)
            const unsigned* fp = flags + rt * 64 + ks * 16 + (lane & 15);
            const unsigned want = (unsigned)p;
            int guard = 0;
            for (;;) {
                const unsigned fv = ld_u32_sc(fp);
                if (__all(fv >= want)) break;
                if (++guard > 8000) break;        // fails visibly, never hangs
                __builtin_amdgcn_s_sleep(1);
            }

            // ---- tagged data fetch + verify (tags prove store completion)
            const size_t off = ((size_t)(((p - 1) & 1) * Bb + (r0 + frow)) * 256
                               + ks * 64 + kgrp * 4) * 2;
            u32x4 d[8];
            guard = 0;
            for (;;) {
                load_tagged8(hb + off, d);
                int ok = 1;
                #pragma unroll
                for (int i = 0; i < 8; ++i)
                    ok &= (d[i].y == want) & (d[i].w == want);
                if (__all(ok)) break;
                if (++guard > 10000) break;       // expected ~0 retries
                __builtin_amdgcn_s_sleep(1);
            }

            // ---- unpack + gate GEMM
            f16x8 a[4];
            #pragma unroll
            for (int kk = 0; kk < 4; ++kk) {
                union { f16x8 v; unsigned u[4]; } t;
                t.u[0] = d[2 * kk].x;     t.u[1] = d[2 * kk].z;
                t.u[2] = d[2 * kk + 1].x; t.u[3] = d[2 * kk + 1].z;
                a[kk] = t.v;
            }
            f32x4 acc[10];
            #pragma unroll
            for (int n = 0; n < 10; ++n) acc[n] = (f32x4){0.f, 0.f, 0.f, 0.f};
            #pragma unroll
            for (int kk = 0; kk < 4; ++kk) {
                #pragma unroll
                for (int n = 0; n < 10; ++n)
                    acc[n] = __builtin_amdgcn_mfma_f32_16x16x32_f16(
                        a[kk], Bf[n][kk], acc[n], 0, 0, 0);
            }
            #pragma unroll
            for (int n = 0; n < 10; ++n)
                #pragma unroll
                for (int r = 0; r < 4; ++r)
                    red[ks][n][kgrp * 4 + r][frow] = acc[n][r];
        }
        __syncthreads();   // red visible to all waves

        // ---- elementwise: thread = (row erow, cols ecp, ecp+1)
        const int   e  = ev_lds[erow][p];
        const float dt = dt_lds[erow][p];
        const int   sc = (e & 7) << 2;
        float hn[2];
        {
            float v0[5], v1[5];
            const int tl0 = ecp >> 4, fc = ecp & 15;
            #pragma unroll
            for (int gt = 0; gt < 5; ++gt) {
                const float2 gv = *(const float2*)&gx[e][gt][ecp ^ sc];
                v0[gt] = gv.x; v1[gt] = gv.y;
                if (p > 0) {
                    const int tl = gt * 2 + tl0;
                    #pragma unroll
                    for (int s = 0; s < 4; ++s) {
                        const float2 pr = *(const float2*)&red[s][tl][erow][fc];
                        v0[gt] += pr.x; v1[gt] += pr.y;
                    }
                }
            }
            #pragma unroll
            for (int q = 0; q < 2; ++q) {
                const float* v = q ? v1 : v0;
                const float ig  = fast_tanh(v[0]);
                const float fg  = fast_tanh(v[1]);
                const float og  = fast_tanh(v[2]);
                const float ctl = fast_tanh(v[3]);
                const float dec = softplusf(v[4]);
                const float cpv = q ? cB : cA;
                const float cn  = fg * (cpv * __expf(-dec * dt)) + ig * ctl;
                if (q) cB = cn; else cA = cn;
                hn[q] = og * fast_tanh(cn);
            }
        }

        // ---- publish: out_hid plain; tagged h unit; per-WAVE flag. NO drain.
        float2 ho; ho.x = hn[0]; ho.y = hn[1];
        *(float2*)(out_hid + ((size_t)(r0 + erow) * Tt + p) * Hh + ct * CT + ecp) = ho;
        const unsigned pk = (unsigned)f2h(hn[0]) | ((unsigned)f2h(hn[1]) << 16);
        st_tag(hb + ((size_t)((p & 1) * Bb + (r0 + erow)) * 256
                     + ct * 16 + (ecp >> 1)) * 2, pk, (unsigned)(p + 1));
        if (lane == 0)
            st_u32_sc(&flags[rt * 64 + ct * 4 + ks], (unsigned)(p + 1));

        __syncthreads();   // red protect (AFTER flag -> overlaps fabric)
    }
}

// out_int = softplus(out_hid @ Wi + bi) as MFMA GEMM. 1024 blocks x 128 rows.
__global__ __launch_bounds__(NTHR)
void nhp_intens(const float* __restrict__ out_hid, const float* __restrict__ Wi,
                const float* __restrict__ bi, float* __restrict__ out_int) {
    const int tid  = threadIdx.x;
    const int w    = tid >> 6;
    const int lane = tid & 63;
    const int col  = lane & 15, kgrp = lane >> 4;

    f16x8 Bfi[2][16];
    #pragma unroll
    for (int n = 0; n < 2; ++n)
        #pragma unroll
        for (int kk = 0; kk < 16; ++kk) {
            const int k0 = kk * 32 + kgrp * 8;
            union { f16x8 v; unsigned u[4]; } tmp;
            #pragma unroll
            for (int r = 0; r < 4; ++r) {
                const float w0 = Wi[(size_t)(k0 + 2 * r)     * Ee + n * 16 + col];
                const float w1 = Wi[(size_t)(k0 + 2 * r + 1) * Ee + n * 16 + col];
                tmp.u[r] = (unsigned)f2h(w0) | ((unsigned)f2h(w1) << 16);
            }
            Bfi[n][kk] = tmp.v;
        }
    const float bv[2] = { bi[col], bi[16 + col] };

    #pragma unroll
    for (int it = 0; it < 2; ++it) {
        const size_t rowbase = (size_t)blockIdx.x * 128 + (w * 2 + it) * 16;
        f32x4 acc0 = (f32x4){0.f,0.f,0.f,0.f}, acc1 = acc0;
        #pragma unroll
        for (int kk = 0; kk < 16; ++kk) {
            const float* hp = out_hid + (rowbase + (lane & 15)) * Hh + kk * 32 + kgrp * 8;
            const float4 hA = *(const float4*)hp;
            const float4 hB = *(const float4*)(hp + 4);
            union { f16x8 v; unsigned u[4]; } t;
            t.u[0] = (unsigned)f2h(hA.x) | ((unsigned)f2h(hA.y) << 16);
            t.u[1] = (unsigned)f2h(hA.z) | ((unsigned)f2h(hA.w) << 16);
            t.u[2] = (unsigned)f2h(hB.x) | ((unsigned)f2h(hB.y) << 16);
            t.u[3] = (unsigned)f2h(hB.z) | ((unsigned)f2h(hB.w) << 16);
            acc0 = __builtin_amdgcn_mfma_f32_16x16x32_f16(t.v, Bfi[0][kk], acc0, 0, 0, 0);
            acc1 = __builtin_amdgcn_mfma_f32_16x16x32_f16(t.v, Bfi[1][kk], acc1, 0, 0, 0);
        }
        #pragma unroll
        for (int i = 0; i < 4; ++i) {
            const size_t row = rowbase + kgrp * 4 + i;
            out_int[row * Ee + col]      = softplusf(acc0[i] + bv[0]);
            out_int[row * Ee + 16 + col] = softplusf(acc1[i] + bv[1]);
        }
    }
}

extern "C" void kernel_launch(void* const* d_in, const int* in_sizes, int n_in,
                              void* d_out, int out_size, void* d_ws, size_t ws_size,
                              hipStream_t stream) {
    const int*   events = (const int*)d_in[0];
    const float* times  = (const float*)d_in[1];
    const float* emb    = (const float*)d_in[2];
    const float* Wg     = (const float*)d_in[3];
    const float* bg     = (const float*)d_in[4];
    const float* Wi     = (const float*)d_in[5];
    const float* bi     = (const float*)d_in[6];
    float* out_int = (float*)d_out;
    float* out_hid = out_int + (size_t)Bb * Tt * Ee;
    unsigned* flags = (unsigned*)d_ws;                    // 1024 words, 4KB
    unsigned* hb = (unsigned*)((char*)d_ws + 4096);       // 2x256x256 units x8B = 1MB

    // clear flags + hb tags (replay-deterministic)
    hipMemsetAsync(d_ws, 0, 4096 + (size_t)2 * Bb * 256 * 8, stream);
    hipLaunchKernelGGL(nhp_scan, dim3(256), dim3(NTHR), 0, stream,
                       events, times, emb, Wg, bg, out_hid, flags, hb);
    hipLaunchKernelGGL(nhp_intens, dim3((Bb * Tt) / 128), dim3(NTHR), 0, stream,
                       out_hid, Wi, bi, out_int);
}

// Round 14
// 2801.546 us; speedup vs baseline: 1.2308x; 1.2308x over previous
//
#include <hip/hip_runtime.h>
#include <math.h>

// Neural Hawkes scan. B=256,T=512,H=512,E=32.
// R14 = R9 (best verified, 2264us) + wave-granular publish ONLY:
//  - each wave drains ITS OWN h stores (vmcnt(0)) then publishes ITS flag
//    (no block-sync between drain and flag; the red-protect __syncthreads
//    moves after the flag store, overlapping flag propagation).
//  - consumer wave ks polls its 16 producer-wave flags: one 64B line.
//  - data fetch stays single-shot tagless (drain-before-flag guarantees
//    visibility at L3 -- the R13 failure mode is structurally excluded).
// All carriers sc0 sc1 (R4/R7/R12: consumer-cacheable polling unusable).
// All spins watchdogged within time budget (R12 lesson).

#define Bb   256
#define Tt   512
#define Hh   512
#define Ee   32
#define G5H  2560
#define NTHR 256
#define RT   16
#define CT   32

typedef __attribute__((ext_vector_type(8))) short f16x8;
typedef __attribute__((ext_vector_type(4))) float f32x4;

__device__ __forceinline__ float softplusf(float x) {
    return fmaxf(x, 0.f) + __logf(1.f + __expf(-fabsf(x)));
}
__device__ __forceinline__ float fast_tanh(float x) {
    const float t = fminf(fmaxf(x, -15.f), 15.f);
    const float e = __expf(2.f * t);
    return (e - 1.f) / (e + 1.f);
}
__device__ __forceinline__ unsigned short f2h(float f) {
    _Float16 h = (_Float16)f;
    return *reinterpret_cast<unsigned short*>(&h);
}

// 4x 16B L3-coherent data loads (lane's 4 k-chunks, 64B stride). R3-proven.
__device__ __forceinline__ void load_a4(const unsigned short* p, f16x8 (&a)[4]) {
    asm volatile(
        "global_load_dwordx4 %0, %4, off sc0 sc1\n\t"
        "global_load_dwordx4 %1, %4, off offset:64 sc0 sc1\n\t"
        "global_load_dwordx4 %2, %4, off offset:128 sc0 sc1\n\t"
        "global_load_dwordx4 %3, %4, off offset:192 sc0 sc1\n\t"
        "s_waitcnt vmcnt(0)"
        : "=&v"(a[0]), "=&v"(a[1]), "=&v"(a[2]), "=&v"(a[3])
        : "v"(p) : "memory");
}
__device__ __forceinline__ void st_u32_sc(void* p, unsigned v) {
    asm volatile("global_store_dword %0, %1, off sc0 sc1"
                 :: "v"(p), "v"(v) : "memory");
}
__device__ __forceinline__ unsigned ld_u32_sc(const unsigned* p) {
    unsigned v;
    asm volatile("global_load_dword %0, %1, off sc0 sc1\n\ts_waitcnt vmcnt(0)"
                 : "=v"(v) : "v"(p) : "memory");
    return v;
}

__global__ __launch_bounds__(NTHR, 1)
void nhp_scan(const int* __restrict__ events, const float* __restrict__ times,
              const float* __restrict__ emb, const float* __restrict__ Wg,
              const float* __restrict__ bg, float* __restrict__ out_hid,
              unsigned* __restrict__ flags, unsigned short* __restrict__ hb) {
    __shared__ float red[4][10][16][18];        // [ksplit][tile][row][col+pad] 46KB
    __shared__ float gx[Ee][5][34];             // col XOR-swizzled by (e&7)<<2
    __shared__ float dt_lds[RT][516];           // all dt, bank-padded
    __shared__ unsigned char ev_lds[RT][520];   // all events

    const int tid  = threadIdx.x, bid = blockIdx.x;
    const int rt   = bid & 15;        // row group
    const int ct   = bid >> 4;        // col tile
    const int r0   = rt * RT;
    const int lane = tid & 63;
    const int ks   = tid >> 6;        // wave id == 4-way K split
    const int frow = lane & 15, kgrp = lane >> 4;
    const int erow = tid >> 4;        // elementwise row 0..15
    const int ecp  = (tid & 15) * 2;  // elementwise col pair

    // ---- one-time: precache events + dt for this block's 16 rows (all T)
    for (int u = tid; u < RT * Tt; u += NTHR) {
        const int row = u >> 9, pp = u & 511;
        const float t1 = times[(r0 + row) * Tt + pp];
        const float t0 = pp ? times[(r0 + row) * Tt + pp - 1] : 0.f;
        dt_lds[row][pp] = t1 - t0;
        ev_lds[row][pp] = (unsigned char)events[(r0 + row) * Tt + pp];
    }

    // ---- one-time: gx[e][g][hc] = emb[e] @ Wx[:,col] + b (XOR-swizzled store)
    for (int u = tid; u < Ee * 5 * CT; u += NTHR) {
        const int e = u / 160, r = u - e * 160;
        const int g = r >> 5, hc = r & 31;
        const int gcol = g * Hh + ct * CT + hc;
        float acc = bg[gcol];
        const float* er = emb + (size_t)e * Hh;
        for (int k = 0; k < Hh; k += 4) {
            acc += er[k]     * Wg[(size_t)k       * G5H + gcol];
            acc += er[k + 1] * Wg[(size_t)(k + 1) * G5H + gcol];
            acc += er[k + 2] * Wg[(size_t)(k + 2) * G5H + gcol];
            acc += er[k + 3] * Wg[(size_t)(k + 3) * G5H + gcol];
        }
        gx[e][g][hc ^ ((e & 7) << 2)] = acc;
    }

    // ---- one-time: Wh fp16 B-fragments, register-resident for all T steps
    f16x8 Bf[10][4];
    #pragma unroll
    for (int n = 0; n < 10; ++n) {
        const int col = (n >> 1) * Hh + ct * CT + (n & 1) * 16 + frow;
        #pragma unroll
        for (int kk = 0; kk < 4; ++kk) {
            const int k0 = ks * 128 + kk * 32 + kgrp * 8;
            union { f16x8 v; unsigned u[4]; } tmp;
            #pragma unroll
            for (int r = 0; r < 4; ++r) {
                const float w0 = Wg[(size_t)(Hh + k0 + 2 * r)     * G5H + col];
                const float w1 = Wg[(size_t)(Hh + k0 + 2 * r + 1) * G5H + col];
                tmp.u[r] = (unsigned)f2h(w0) | ((unsigned)f2h(w1) << 16);
            }
            Bf[n][kk] = tmp.v;
        }
    }

    float cA = 0.f, cB = 0.f;
    __syncthreads();

    for (int p = 0; p < Tt; ++p) {
        if (p > 0) {
            // ---- poll 16 producer-WAVE flags (blocks 4ks..4ks+3 x waves 0..3)
            //      = flags[rt*64 + 16ks .. +16): one contiguous 64B line
            const unsigned* fp = flags + rt * 64 + ks * 16 + (lane & 15);
            const unsigned want = (unsigned)p;
            int guard = 0;
            for (;;) {
                const unsigned fv = ld_u32_sc(fp);
                if (__all(fv >= want)) break;
                if (++guard > 6000) break;        // fails visibly, never hangs
                __builtin_amdgcn_s_sleep(1);
            }

            // ---- single tagless data fetch (drain-before-flag => visible)
            const unsigned short* hp = hb + (size_t)((p - 1) & 1) * Bb * Hh
                                     + (size_t)(r0 + frow) * Hh + ks * 128 + kgrp * 8;
            f16x8 a[4];
            load_a4(hp, a);

            // ---- gate GEMM
            f32x4 acc[10];
            #pragma unroll
            for (int n = 0; n < 10; ++n) acc[n] = (f32x4){0.f, 0.f, 0.f, 0.f};
            #pragma unroll
            for (int kk = 0; kk < 4; ++kk) {
                #pragma unroll
                for (int n = 0; n < 10; ++n)
                    acc[n] = __builtin_amdgcn_mfma_f32_16x16x32_f16(
                        a[kk], Bf[n][kk], acc[n], 0, 0, 0);
            }
            #pragma unroll
            for (int n = 0; n < 10; ++n)
                #pragma unroll
                for (int r = 0; r < 4; ++r)
                    red[ks][n][kgrp * 4 + r][frow] = acc[n][r];
        }
        __syncthreads();   // red visible to all waves

        // ---- elementwise: thread = (row erow, cols ecp, ecp+1)
        const int   e  = ev_lds[erow][p];
        const float dt = dt_lds[erow][p];
        const int   sc = (e & 7) << 2;
        float hn[2];
        {
            float v0[5], v1[5];
            const int tl0 = ecp >> 4, fc = ecp & 15;
            #pragma unroll
            for (int gt = 0; gt < 5; ++gt) {
                const float2 gv = *(const float2*)&gx[e][gt][ecp ^ sc];
                v0[gt] = gv.x; v1[gt] = gv.y;
                if (p > 0) {
                    const int tl = gt * 2 + tl0;
                    #pragma unroll
                    for (int s = 0; s < 4; ++s) {
                        const float2 pr = *(const float2*)&red[s][tl][erow][fc];
                        v0[gt] += pr.x; v1[gt] += pr.y;
                    }
                }
            }
            #pragma unroll
            for (int q = 0; q < 2; ++q) {
                const float* v = q ? v1 : v0;
                const float ig  = fast_tanh(v[0]);
                const float fg  = fast_tanh(v[1]);
                const float og  = fast_tanh(v[2]);
                const float ctl = fast_tanh(v[3]);
                const float dec = softplusf(v[4]);
                const float cpv = q ? cB : cA;
                const float cn  = fg * (cpv * __expf(-dec * dt)) + ig * ctl;
                if (q) cB = cn; else cA = cn;
                hn[q] = og * fast_tanh(cn);
            }
        }

        // ---- stores: out_hid plain (L2 writeback), h tagless sc0sc1 (L3)
        float2 ho; ho.x = hn[0]; ho.y = hn[1];
        *(float2*)(out_hid + ((size_t)(r0 + erow) * Tt + p) * Hh + ct * CT + ecp) = ho;
        const unsigned pk = (unsigned)f2h(hn[0]) | ((unsigned)f2h(hn[1]) << 16);
        st_u32_sc(hb + (size_t)(p & 1) * Bb * Hh
                     + (size_t)(r0 + erow) * Hh + ct * CT + ecp, pk);

        // ---- per-WAVE drain + per-WAVE flag (no block sync on publish path)
        asm volatile("s_waitcnt vmcnt(0)" ::: "memory");
        if (lane == 0)
            st_u32_sc(&flags[rt * 64 + ct * 4 + ks], (unsigned)(p + 1));

        __syncthreads();   // red protect (AFTER flag -> overlaps propagation)
    }
}

// out_int = softplus(out_hid @ Wi + bi) as MFMA GEMM. 1024 blocks x 128 rows.
__global__ __launch_bounds__(NTHR)
void nhp_intens(const float* __restrict__ out_hid, const float* __restrict__ Wi,
                const float* __restrict__ bi, float* __restrict__ out_int) {
    const int tid  = threadIdx.x;
    const int w    = tid >> 6;
    const int lane = tid & 63;
    const int col  = lane & 15, kgrp = lane >> 4;

    f16x8 Bfi[2][16];
    #pragma unroll
    for (int n = 0; n < 2; ++n)
        #pragma unroll
        for (int kk = 0; kk < 16; ++kk) {
            const int k0 = kk * 32 + kgrp * 8;
            union { f16x8 v; unsigned u[4]; } tmp;
            #pragma unroll
            for (int r = 0; r < 4; ++r) {
                const float w0 = Wi[(size_t)(k0 + 2 * r)     * Ee + n * 16 + col];
                const float w1 = Wi[(size_t)(k0 + 2 * r + 1) * Ee + n * 16 + col];
                tmp.u[r] = (unsigned)f2h(w0) | ((unsigned)f2h(w1) << 16);
            }
            Bfi[n][kk] = tmp.v;
        }
    const float bv[2] = { bi[col], bi[16 + col] };

    #pragma unroll
    for (int it = 0; it < 2; ++it) {
        const size_t rowbase = (size_t)blockIdx.x * 128 + (w * 2 + it) * 16;
        f32x4 acc0 = (f32x4){0.f,0.f,0.f,0.f}, acc1 = acc0;
        #pragma unroll
        for (int kk = 0; kk < 16; ++kk) {
            const float* hp = out_hid + (rowbase + (lane & 15)) * Hh + kk * 32 + kgrp * 8;
            const float4 hA = *(const float4*)hp;
            const float4 hB = *(const float4*)(hp + 4);
            union { f16x8 v; unsigned u[4]; } t;
            t.u[0] = (unsigned)f2h(hA.x) | ((unsigned)f2h(hA.y) << 16);
            t.u[1] = (unsigned)f2h(hA.z) | ((unsigned)f2h(hA.w) << 16);
            t.u[2] = (unsigned)f2h(hB.x) | ((unsigned)f2h(hB.y) << 16);
            t.u[3] = (unsigned)f2h(hB.z) | ((unsigned)f2h(hB.w) << 16);
            acc0 = __builtin_amdgcn_mfma_f32_16x16x32_f16(t.v, Bfi[0][kk], acc0, 0, 0, 0);
            acc1 = __builtin_amdgcn_mfma_f32_16x16x32_f16(t.v, Bfi[1][kk], acc1, 0, 0, 0);
        }
        #pragma unroll
        for (int i = 0; i < 4; ++i) {
            const size_t row = rowbase + kgrp * 4 + i;
            out_int[row * Ee + col]      = softplusf(acc0[i] + bv[0]);
            out_int[row * Ee + 16 + col] = softplusf(acc1[i] + bv[1]);
        }
    }
}

extern "C" void kernel_launch(void* const* d_in, const int* in_sizes, int n_in,
                              void* d_out, int out_size, void* d_ws, size_t ws_size,
                              hipStream_t stream) {
    const int*   events = (const int*)d_in[0];
    const float* times  = (const float*)d_in[1];
    const float* emb    = (const float*)d_in[2];
    const float* Wg     = (const float*)d_in[3];
    const float* bg     = (const float*)d_in[4];
    const float* Wi     = (const float*)d_in[5];
    const float* bi     = (const float*)d_in[6];
    float* out_int = (float*)d_out;
    float* out_hid = out_int + (size_t)Bb * Tt * Ee;
    unsigned* flags = (unsigned*)d_ws;                          // 1024 words, 4KB
    unsigned short* hb = (unsigned short*)((char*)d_ws + 4096); // 2x256x512 fp16

    hipMemsetAsync(flags, 0, 4096, stream);   // reset flags each launch/replay
    hipLaunchKernelGGL(nhp_scan, dim3(256), dim3(NTHR), 0, stream,
                       events, times, emb, Wg, bg, out_hid, flags, hb);
    hipLaunchKernelGGL(nhp_intens, dim3((Bb * Tt) / 128), dim3(NTHR), 0, stream,
                       out_hid, Wi, bi, out_int);
}

// Round 15
// 2267.150 us; speedup vs baseline: 1.5210x; 1.2357x over previous
//
#include <hip/hip_runtime.h>
#include <math.h>

// Neural Hawkes scan. B=256,T=512,H=512,E=32.
// R15 = R9 VERBATIM (best verified: 2264us). Protocol-variant ledger:
//   R5 atomic-counter 2527 | R6 tagged-only 2469 | R7 L2-dual-publish 8462
//   R8 defer-store 2505 | R9 flag+data split 2264 <- BEST | R10 8-wide 3355
//   R11 speculative 3270 | R12 L2-verified HANG | R13 no-drain 3448
//   R14 wave-flags 2801
// Conclusion: drain -> block-flag -> 4-word poll -> tagless fetch is the
// minimum-latency correct protocol on this fabric. Step floor ~4.4us =
// ~4 loaded-L3 round-trips (sc0sc1 carrier, the only correct one: R4/R7/R12
// prove consumer-cacheable polling unusable) + max-of-16 skew + compute.
// Structural: W (2.6MB) >> one CU's 512KB regfile/160KB LDS => row-group
// GEMM spans 16 CUs => per-step cross-CU exchange through L3 is mandatory.

#define Bb   256
#define Tt   512
#define Hh   512
#define Ee   32
#define G5H  2560
#define NTHR 256
#define RT   16
#define CT   32

typedef __attribute__((ext_vector_type(8))) short f16x8;
typedef __attribute__((ext_vector_type(4))) float f32x4;

__device__ __forceinline__ float softplusf(float x) {
    return fmaxf(x, 0.f) + __logf(1.f + __expf(-fabsf(x)));
}
__device__ __forceinline__ float fast_tanh(float x) {
    const float t = fminf(fmaxf(x, -15.f), 15.f);
    const float e = __expf(2.f * t);
    return (e - 1.f) / (e + 1.f);
}
__device__ __forceinline__ unsigned short f2h(float f) {
    _Float16 h = (_Float16)f;
    return *reinterpret_cast<unsigned short*>(&h);
}

// 4x 16B L3-coherent data loads (lane's 4 k-chunks, 64B stride). R3-proven.
__device__ __forceinline__ void load_a4(const unsigned short* p, f16x8 (&a)[4]) {
    asm volatile(
        "global_load_dwordx4 %0, %4, off sc0 sc1\n\t"
        "global_load_dwordx4 %1, %4, off offset:64 sc0 sc1\n\t"
        "global_load_dwordx4 %2, %4, off offset:128 sc0 sc1\n\t"
        "global_load_dwordx4 %3, %4, off offset:192 sc0 sc1\n\t"
        "s_waitcnt vmcnt(0)"
        : "=&v"(a[0]), "=&v"(a[1]), "=&v"(a[2]), "=&v"(a[3])
        : "v"(p) : "memory");
}
__device__ __forceinline__ void st_u32_sc(void* p, unsigned v) {
    asm volatile("global_store_dword %0, %1, off sc0 sc1"
                 :: "v"(p), "v"(v) : "memory");
}
__device__ __forceinline__ unsigned ld_u32_sc(const unsigned* p) {
    unsigned v;
    asm volatile("global_load_dword %0, %1, off sc0 sc1\n\ts_waitcnt vmcnt(0)"
                 : "=v"(v) : "v"(p) : "memory");
    return v;
}

__global__ __launch_bounds__(NTHR, 1)
void nhp_scan(const int* __restrict__ events, const float* __restrict__ times,
              const float* __restrict__ emb, const float* __restrict__ Wg,
              const float* __restrict__ bg, float* __restrict__ out_hid,
              unsigned* __restrict__ flags, unsigned short* __restrict__ hb) {
    __shared__ float red[4][10][16][18];        // [ksplit][tile][row][col+pad] 46KB
    __shared__ float gx[Ee][5][34];             // col XOR-swizzled by (e&7)<<2
    __shared__ float dt_lds[RT][516];           // all dt, bank-padded
    __shared__ unsigned char ev_lds[RT][520];   // all events

    const int tid  = threadIdx.x, bid = blockIdx.x;
    const int rt   = bid & 15;        // row group
    const int ct   = bid >> 4;        // col tile
    const int r0   = rt * RT;
    const int lane = tid & 63;
    const int ks   = tid >> 6;        // 4-way K split: k in [ks*128, +128)
    const int frow = lane & 15, kgrp = lane >> 4;
    const int erow = tid >> 4;        // elementwise row 0..15
    const int ecp  = (tid & 15) * 2;  // elementwise col pair

    // ---- one-time: precache events + dt for this block's 16 rows (all T)
    for (int u = tid; u < RT * Tt; u += NTHR) {
        const int row = u >> 9, pp = u & 511;
        const float t1 = times[(r0 + row) * Tt + pp];
        const float t0 = pp ? times[(r0 + row) * Tt + pp - 1] : 0.f;
        dt_lds[row][pp] = t1 - t0;
        ev_lds[row][pp] = (unsigned char)events[(r0 + row) * Tt + pp];
    }

    // ---- one-time: gx[e][g][hc] = emb[e] @ Wx[:,col] + b (XOR-swizzled store)
    for (int u = tid; u < Ee * 5 * CT; u += NTHR) {
        const int e = u / 160, r = u - e * 160;
        const int g = r >> 5, hc = r & 31;
        const int gcol = g * Hh + ct * CT + hc;
        float acc = bg[gcol];
        const float* er = emb + (size_t)e * Hh;
        for (int k = 0; k < Hh; k += 4) {
            acc += er[k]     * Wg[(size_t)k       * G5H + gcol];
            acc += er[k + 1] * Wg[(size_t)(k + 1) * G5H + gcol];
            acc += er[k + 2] * Wg[(size_t)(k + 2) * G5H + gcol];
            acc += er[k + 3] * Wg[(size_t)(k + 3) * G5H + gcol];
        }
        gx[e][g][hc ^ ((e & 7) << 2)] = acc;
    }

    // ---- one-time: Wh fp16 B-fragments, register-resident for all T steps
    f16x8 Bf[10][4];
    #pragma unroll
    for (int n = 0; n < 10; ++n) {
        const int col = (n >> 1) * Hh + ct * CT + (n & 1) * 16 + frow;
        #pragma unroll
        for (int kk = 0; kk < 4; ++kk) {
            const int k0 = ks * 128 + kk * 32 + kgrp * 8;
            union { f16x8 v; unsigned u[4]; } tmp;
            #pragma unroll
            for (int r = 0; r < 4; ++r) {
                const float w0 = Wg[(size_t)(Hh + k0 + 2 * r)     * G5H + col];
                const float w1 = Wg[(size_t)(Hh + k0 + 2 * r + 1) * G5H + col];
                tmp.u[r] = (unsigned)f2h(w0) | ((unsigned)f2h(w1) << 16);
            }
            Bf[n][kk] = tmp.v;
        }
    }

    float cA = 0.f, cB = 0.f;
    __syncthreads();

    for (int p = 0; p < Tt; ++p) {
        if (p > 0) {
            // ---- cheap flag poll: wave ks needs producers ct' = ks*4..ks*4+3
            const unsigned* fp = flags + rt * 16 + ks * 4 + (lane & 3);
            const unsigned want = (unsigned)p;     // flag = steps completed
            int guard = 0;
            for (;;) {
                const unsigned fv = ld_u32_sc(fp);
                if (__all(fv >= want)) break;
                if (++guard > 300000) break;       // never hang the bench
                __builtin_amdgcn_s_sleep(1);
            }

            // ---- single tagless data fetch: h_{p-1}[r0+frow, ks*128+..]
            const unsigned short* hp = hb + (size_t)((p - 1) & 1) * Bb * Hh
                                     + (size_t)(r0 + frow) * Hh + ks * 128 + kgrp * 8;
            f16x8 a[4];
            load_a4(hp, a);

            // ---- gate GEMM
            f32x4 acc[10];
            #pragma unroll
            for (int n = 0; n < 10; ++n) acc[n] = (f32x4){0.f, 0.f, 0.f, 0.f};
            #pragma unroll
            for (int kk = 0; kk < 4; ++kk) {
                #pragma unroll
                for (int n = 0; n < 10; ++n)
                    acc[n] = __builtin_amdgcn_mfma_f32_16x16x32_f16(
                        a[kk], Bf[n][kk], acc[n], 0, 0, 0);
            }
            // prior step's red reads were joined by last step's end-sync
            #pragma unroll
            for (int n = 0; n < 10; ++n)
                #pragma unroll
                for (int r = 0; r < 4; ++r)
                    red[ks][n][kgrp * 4 + r][frow] = acc[n][r];
        }
        __syncthreads();   // red visible to all waves

        // ---- elementwise: thread = (row erow, cols ecp, ecp+1)
        const int   e  = ev_lds[erow][p];
        const float dt = dt_lds[erow][p];
        const int   sc = (e & 7) << 2;
        float hn[2];
        {
            float v0[5], v1[5];
            const int tl0 = ecp >> 4, fc = ecp & 15;
            #pragma unroll
            for (int gt = 0; gt < 5; ++gt) {
                const float2 gv = *(const float2*)&gx[e][gt][ecp ^ sc];
                v0[gt] = gv.x; v1[gt] = gv.y;
                if (p > 0) {
                    const int tl = gt * 2 + tl0;
                    #pragma unroll
                    for (int s = 0; s < 4; ++s) {
                        const float2 pr = *(const float2*)&red[s][tl][erow][fc];
                        v0[gt] += pr.x; v1[gt] += pr.y;
                    }
                }
            }
            #pragma unroll
            for (int q = 0; q < 2; ++q) {
                const float* v = q ? v1 : v0;
                const float ig  = fast_tanh(v[0]);
                const float fg  = fast_tanh(v[1]);
                const float og  = fast_tanh(v[2]);
                const float ctl = fast_tanh(v[3]);
                const float dec = softplusf(v[4]);
                const float cpv = q ? cB : cA;
                const float cn  = fg * (cpv * __expf(-dec * dt)) + ig * ctl;
                if (q) cB = cn; else cA = cn;
                hn[q] = og * fast_tanh(cn);
            }
        }

        // ---- stores: out_hid plain (L2 writeback), h tagless sc0sc1 (L3)
        float2 ho; ho.x = hn[0]; ho.y = hn[1];
        *(float2*)(out_hid + ((size_t)(r0 + erow) * Tt + p) * Hh + ct * CT + ecp) = ho;
        const unsigned pk = (unsigned)f2h(hn[0]) | ((unsigned)f2h(hn[1]) << 16);
        st_u32_sc(hb + (size_t)(p & 1) * Bb * Hh
                     + (size_t)(r0 + erow) * Hh + ct * CT + ecp, pk);

        // ---- drain + join + publish completion flag (one word per block)
        asm volatile("s_waitcnt vmcnt(0)" ::: "memory");
        __syncthreads();                            // also frees red for p+1
        if (tid == 0) st_u32_sc(&flags[rt * 16 + ct], (unsigned)(p + 1));
    }
}

// out_int = softplus(out_hid @ Wi + bi) as MFMA GEMM. 1024 blocks x 128 rows.
__global__ __launch_bounds__(NTHR)
void nhp_intens(const float* __restrict__ out_hid, const float* __restrict__ Wi,
                const float* __restrict__ bi, float* __restrict__ out_int) {
    const int tid  = threadIdx.x;
    const int w    = tid >> 6;
    const int lane = tid & 63;
    const int col  = lane & 15, kgrp = lane >> 4;

    f16x8 Bfi[2][16];
    #pragma unroll
    for (int n = 0; n < 2; ++n)
        #pragma unroll
        for (int kk = 0; kk < 16; ++kk) {
            const int k0 = kk * 32 + kgrp * 8;
            union { f16x8 v; unsigned u[4]; } tmp;
            #pragma unroll
            for (int r = 0; r < 4; ++r) {
                const float w0 = Wi[(size_t)(k0 + 2 * r)     * Ee + n * 16 + col];
                const float w1 = Wi[(size_t)(k0 + 2 * r + 1) * Ee + n * 16 + col];
                tmp.u[r] = (unsigned)f2h(w0) | ((unsigned)f2h(w1) << 16);
            }
            Bfi[n][kk] = tmp.v;
        }
    const float bv[2] = { bi[col], bi[16 + col] };

    #pragma unroll
    for (int it = 0; it < 2; ++it) {
        const size_t rowbase = (size_t)blockIdx.x * 128 + (w * 2 + it) * 16;
        f32x4 acc0 = (f32x4){0.f,0.f,0.f,0.f}, acc1 = acc0;
        #pragma unroll
        for (int kk = 0; kk < 16; ++kk) {
            const float* hp = out_hid + (rowbase + (lane & 15)) * Hh + kk * 32 + kgrp * 8;
            const float4 hA = *(const float4*)hp;
            const float4 hB = *(const float4*)(hp + 4);
            union { f16x8 v; unsigned u[4]; } t;
            t.u[0] = (unsigned)f2h(hA.x) | ((unsigned)f2h(hA.y) << 16);
            t.u[1] = (unsigned)f2h(hA.z) | ((unsigned)f2h(hA.w) << 16);
            t.u[2] = (unsigned)f2h(hB.x) | ((unsigned)f2h(hB.y) << 16);
            t.u[3] = (unsigned)f2h(hB.z) | ((unsigned)f2h(hB.w) << 16);
            acc0 = __builtin_amdgcn_mfma_f32_16x16x32_f16(t.v, Bfi[0][kk], acc0, 0, 0, 0);
            acc1 = __builtin_amdgcn_mfma_f32_16x16x32_f16(t.v, Bfi[1][kk], acc1, 0, 0, 0);
        }
        #pragma unroll
        for (int i = 0; i < 4; ++i) {
            const size_t row = rowbase + kgrp * 4 + i;
            out_int[row * Ee + col]      = softplusf(acc0[i] + bv[0]);
            out_int[row * Ee + 16 + col] = softplusf(acc1[i] + bv[1]);
        }
    }
}

extern "C" void kernel_launch(void* const* d_in, const int* in_sizes, int n_in,
                              void* d_out, int out_size, void* d_ws, size_t ws_size,
                              hipStream_t stream) {
    const int*   events = (const int*)d_in[0];
    const float* times  = (const float*)d_in[1];
    const float* emb    = (const float*)d_in[2];
    const float* Wg     = (const float*)d_in[3];
    const float* bg     = (const float*)d_in[4];
    const float* Wi     = (const float*)d_in[5];
    const float* bi     = (const float*)d_in[6];
    float* out_int = (float*)d_out;
    float* out_hid = out_int + (size_t)Bb * Tt * Ee;
    unsigned* flags = (unsigned*)d_ws;                          // 256 words
    unsigned short* hb = (unsigned short*)((char*)d_ws + 4096); // 2x256x512 fp16

    hipMemsetAsync(flags, 0, 4096, stream);   // reset flags each launch/replay
    hipLaunchKernelGGL(nhp_scan, dim3(256), dim3(NTHR), 0, stream,
                       events, times, emb, Wg, bg, out_hid, flags, hb);
    hipLaunchKernelGGL(nhp_intens, dim3((Bb * Tt) / 128), dim3(NTHR), 0, stream,
                       out_hid, Wi, bi, out_int);
}